// Round 7
// baseline (322.993 us; speedup 1.0000x reference)
//
#include <hip/hip_runtime.h>
#include <hip/hip_bf16.h>

// out[512, 65536] = inputs[512,256] @ features[65536,256]^T  (fp32 in/out)
//
// v8: v5's barrier-free structure + NONTEMPORAL B-loads/C-stores (single-
// variable change vs v5, which was HBM-bound on L2-thrash garbage traffic:
// FETCH 259 MB (C write-allocate!) / WRITE 582 MB (dirty eviction churn)).
//   - BN=64: Bs = 32 KB -> 4 blocks/CU, __launch_bounds__(256,4), grid 1024.
//   - B panel staged once (XOR-swizzled, NT loads: read-once, skip L2).
//   - A from bf16 ws: per-step register prefetch (afc/afn) from global; these
//     loads are CACHEABLE -> with B/C streams out of L2, the 256 KB A ws is
//     L2-resident and the prefetch hits ~200cy L2 under the MFMA phase.
//   - C stores NT: no write-allocate fetch, no dirty-line churn.
//   - Main loop: zero barriers, zero LDS-DMA; one __syncthreads after Bs.

#define M_DIM 512
#define N_DIM 65536
#define K_DIM 256
#define BN 64
#define MP 256          // rows per m-pass (4 waves x 64)

typedef __bf16 bf16x8 __attribute__((ext_vector_type(8)));
typedef float f32x4 __attribute__((ext_vector_type(4)));

// ---- kernel 1: inputs [512][256] fp32 -> bf16 ws, row-major ----
__global__ __launch_bounds__(256) void cvt_inputs(const float* __restrict__ A,
                                                  __bf16* __restrict__ Aw) {
    const int t = blockIdx.x * 256 + threadIdx.x;   // 16384 threads x 8 elems
    const float* src = A + (size_t)t * 8;
    f32x4 v0 = *(const f32x4*)src;
    f32x4 v1 = *(const f32x4*)(src + 4);
    bf16x8 h;
    h[0] = (__bf16)v0[0]; h[1] = (__bf16)v0[1];
    h[2] = (__bf16)v0[2]; h[3] = (__bf16)v0[3];
    h[4] = (__bf16)v1[0]; h[5] = (__bf16)v1[1];
    h[6] = (__bf16)v1[2]; h[7] = (__bf16)v1[3];
    *(bf16x8*)(Aw + (size_t)t * 8) = h;
}

__global__ __launch_bounds__(256, 4) void hm_gemm_bt(
    const __bf16* __restrict__ Aw,  // [512][256] bf16 ws (L2-resident)
    const float*  __restrict__ B,   // features [65536][256] fp32
    float* __restrict__ C)          // out [512][65536] fp32
{
    __shared__ __align__(16) __bf16 Bs[BN * K_DIM];  // 32 KB, full-K B panel

    const int tid  = threadIdx.x;
    const int lane = tid & 63;
    const int wave = tid >> 6;            // 4 waves stacked in M
    const int wm   = wave * 64;

    const int n0 = blockIdx.x * BN;       // grid = 1024, one 64-col panel/block

    const int lrow = lane & 15;
    const int lk   = (lane >> 4) * 8;
    const int lx   = lrow & 7;            // XOR key for swizzled Bs reads

    // ---- stage B panel once: 64 rows x 256 k, fp32 -> bf16, swizzled, NT
    #pragma unroll 4
    for (int it = 0; it < 8; ++it) {
        const int c   = it * 256 + tid;   // 0..2047 bf16x8 slots
        const int row = c >> 5;           // 0..63
        const int s   = c & 31;
        const f32x4* src = (const f32x4*)(B + (size_t)(n0 + row) * K_DIM + s * 8);
        f32x4 v0 = __builtin_nontemporal_load(src);
        f32x4 v1 = __builtin_nontemporal_load(src + 1);
        bf16x8 h;
        h[0] = (__bf16)v0[0]; h[1] = (__bf16)v0[1];
        h[2] = (__bf16)v0[2]; h[3] = (__bf16)v0[3];
        h[4] = (__bf16)v1[0]; h[5] = (__bf16)v1[1];
        h[6] = (__bf16)v1[2]; h[7] = (__bf16)v1[3];
        const int sst = s ^ (row & 7);
        *(bf16x8*)&Bs[row * K_DIM + sst * 8] = h;
    }
    __syncthreads();                      // Bs read-only from here: no more barriers

    for (int mp = 0; mp < M_DIM / MP; ++mp) {
        f32x4 acc[4][4];
        #pragma unroll
        for (int i = 0; i < 4; ++i)
            #pragma unroll
            for (int j = 0; j < 4; ++j)
                acc[i][j] = f32x4{0.f, 0.f, 0.f, 0.f};

        const __bf16* Ab = Aw + (size_t)(mp * MP + wm + lrow) * K_DIM + lk;

        // prologue: prefetch k=0 A fragments into registers (L2 hits)
        bf16x8 afc[4], afn[4];
        #pragma unroll
        for (int i = 0; i < 4; ++i)
            afc[i] = *(const bf16x8*)(Ab + (size_t)(i * 16) * K_DIM);

        #pragma unroll
        for (int k = 0; k < K_DIM; k += 32) {
            // issue next step's A loads first (L2 latency hides under this step)
            if (k + 32 < K_DIM) {
                #pragma unroll
                for (int i = 0; i < 4; ++i)
                    afn[i] = *(const bf16x8*)(Ab + (size_t)(i * 16) * K_DIM
                                                 + (k + 32));
            }
            bf16x8 bfr[4];
            #pragma unroll
            for (int j = 0; j < 4; ++j) {
                const int row = j * 16 + lrow;
                const int pos = (((k + lk) >> 3) ^ lx);
                bfr[j] = *(const bf16x8*)&Bs[row * K_DIM + pos * 8];
            }
            #pragma unroll
            for (int i = 0; i < 4; ++i)
                #pragma unroll
                for (int j = 0; j < 4; ++j)
                    acc[i][j] = __builtin_amdgcn_mfma_f32_16x16x32_bf16(
                        bfr[j], afc[i], acc[i][j], 0, 0, 0);  // D.row -> n
            #pragma unroll
            for (int i = 0; i < 4; ++i)
                afc[i] = afn[i];
        }

        // ---- epilogue: NT f32x4 stores (no write-allocate, no L2 churn)
        const int lm = lane & 15;
        const int ln = (lane >> 4) * 4;
        #pragma unroll
        for (int i = 0; i < 4; ++i) {
            const size_t rowbase = (size_t)(mp * MP + wm + i * 16 + lm) * N_DIM;
            #pragma unroll
            for (int j = 0; j < 4; ++j) {
                f32x4* dst = (f32x4*)(C + rowbase + (n0 + j * 16 + ln));
                __builtin_nontemporal_store(acc[i][j], dst);
            }
        }
    }
}

extern "C" void kernel_launch(void* const* d_in, const int* in_sizes, int n_in,
                              void* d_out, int out_size, void* d_ws, size_t ws_size,
                              hipStream_t stream) {
    // setup_inputs order: inputs, indexes, features, mIoU, IoU
    const float* inputs   = (const float*)d_in[0];
    const float* features = (const float*)d_in[2];
    float* out = (float*)d_out;
    __bf16* Aw = (__bf16*)d_ws;          // 256 KB of workspace

    hipLaunchKernelGGL(cvt_inputs, dim3(M_DIM * K_DIM / (256 * 8)), dim3(256),
                       0, stream, inputs, Aw);

    hipLaunchKernelGGL(hm_gemm_bt, dim3(N_DIM / BN), dim3(256), 0, stream,
                       Aw, features, out);
}

// Round 8
// 197.204 us; speedup vs baseline: 1.6379x; 1.6379x over previous
//
#include <hip/hip_runtime.h>
#include <hip/hip_bf16.h>

// out[512, 65536] = inputs[512,256] @ features[65536,256]^T  (fp32 in/out)
//
// v9: v3's proven structure (A via global_load_lds DMA, per-step barriers,
// BN=128, B read from HBM exactly once, all 512 blocks co-resident) with the
// two phase-overlap fixes the 42-vs-31us gap pointed at:
//   - As[2] double-buffer at BK=32 (80 KB LDS total, 2 blocks/CU): step t
//     issues t+1's DMA at step START; the end-of-step __syncthreads (compiler
//     emits s_waitcnt vmcnt(0)) lands it -> DMA latency hidden under compute.
//     One barrier per step. No inline-asm waits (placement-proof).
//   - C stores spread: each mp's 16 f32x4 stores issue 2-per-step during the
//     NEXT mp's k-steps (accs shadow copy) -> write stream flows continuously
//     instead of 4 bursts; reads/writes/compute overlap.
//   - BK=32 As rows are 64 B -> naturally bank-conflict-free, NO swizzle
//     (linear DMA dest + linear source + linear read). Bs keeps v3's XOR.

#define M_DIM 512
#define N_DIM 65536
#define K_DIM 256
#define BN 128
#define BK 32

typedef __bf16 bf16x8 __attribute__((ext_vector_type(8)));
typedef float f32x4 __attribute__((ext_vector_type(4)));

// ---- kernel 1: inputs [512][256] fp32 -> bf16 ws, row-major ----
__global__ __launch_bounds__(256) void cvt_inputs(const float* __restrict__ A,
                                                  __bf16* __restrict__ Aw) {
    const int t = blockIdx.x * 256 + threadIdx.x;   // 16384 threads x 8 elems
    const float* src = A + (size_t)t * 8;
    f32x4 v0 = *(const f32x4*)src;
    f32x4 v1 = *(const f32x4*)(src + 4);
    bf16x8 h;
    h[0] = (__bf16)v0[0]; h[1] = (__bf16)v0[1];
    h[2] = (__bf16)v0[2]; h[3] = (__bf16)v0[3];
    h[4] = (__bf16)v1[0]; h[5] = (__bf16)v1[1];
    h[6] = (__bf16)v1[2]; h[7] = (__bf16)v1[3];
    *(bf16x8*)(Aw + (size_t)t * 8) = h;
}

static __device__ __forceinline__ void gload_lds16(const __bf16* g, __bf16* l) {
    __builtin_amdgcn_global_load_lds(
        (const __attribute__((address_space(1))) void*)g,
        (__attribute__((address_space(3))) void*)l, 16, 0, 0);
}

__global__ __launch_bounds__(256, 2) void hm_gemm_bt(
    const __bf16* __restrict__ Aw,  // [512][256] bf16 ws
    const float*  __restrict__ B,   // features [65536][256] fp32
    float* __restrict__ C)          // out [512][65536] fp32
{
    __shared__ __align__(16) __bf16 Bs[BN * K_DIM];   // 64 KB, full-K B panel
    __shared__ __align__(16) __bf16 As[2][128 * BK];  // 2 x 8 KB, linear

    const int tid  = threadIdx.x;
    const int lane = tid & 63;
    const int wave = tid >> 6;            // 4 waves, 2x2 grid of 64x64 subtiles
    const int wm   = (wave >> 1) * 64;
    const int wn   = (wave & 1) * 64;
    const int n0   = blockIdx.x * BN;     // grid = 512, all co-resident

    const int lrow = lane & 15;
    const int lx   = lane & 7;            // Bs XOR key (row&7 == lane&7)

    // A-DMA lane geometry: chunk c (1 KB): lane l writes LDS elems c*512+l*8
    // -> row_local = c*16 + (l>>2), k-elems (l&3)*8. Linear both sides.
    const int ar = lane >> 2;
    const int ak = (lane & 3) * 8;

    // ---- issue step-0 A tile DMA first: flies during Bs staging
    #pragma unroll
    for (int q = 0; q < 2; ++q) {
        const int c = wave * 2 + q;
        gload_lds16(Aw + (size_t)(c * 16 + ar) * K_DIM + ak, &As[0][c * 512]);
    }

    // ---- stage full-K B panel once: 128 rows x 256 k, fp32 -> bf16, XOR-swz
    #pragma unroll 4
    for (int it = 0; it < 16; ++it) {
        const int cc  = it * 256 + tid;   // 0..4095 bf16x8 slots
        const int row = cc >> 5;
        const int s   = cc & 31;
        const float* src = B + (size_t)(n0 + row) * K_DIM + s * 8;
        f32x4 v0 = *(const f32x4*)(src);
        f32x4 v1 = *(const f32x4*)(src + 4);
        bf16x8 h;
        h[0] = (__bf16)v0[0]; h[1] = (__bf16)v0[1];
        h[2] = (__bf16)v0[2]; h[3] = (__bf16)v0[3];
        h[4] = (__bf16)v1[0]; h[5] = (__bf16)v1[1];
        h[6] = (__bf16)v1[2]; h[7] = (__bf16)v1[3];
        const int sst = s ^ (row & 7);
        *(bf16x8*)&Bs[row * K_DIM + sst * 8] = h;
    }
    __syncthreads();   // drains vmcnt(0): Bs AND step-0 A tile ready

    f32x4 acc[4][4], accs[4][4];

    // ---- 32 steps: t -> (mp = t>>3, kb = t&7). One barrier per step.
    #pragma unroll
    for (int t = 0; t < 32; ++t) {
        const int mp = t >> 3;
        const int kb = t & 7;

        // issue NEXT step's A-DMA into the other buffer (hidden under compute,
        // landed by this step's end barrier). Writes As[(t+1)&1]; current
        // reads hit As[t&1] -> no race; re-write of As[t&1] (step t+2's DMA)
        // is issued only after this step's end barrier.
        if (t < 31) {
            const int tn  = t + 1;
            const int mpn = tn >> 3;
            const int kbn = tn & 7;
            #pragma unroll
            for (int q = 0; q < 2; ++q) {
                const int c = wave * 2 + q;
                gload_lds16(Aw + (size_t)(mpn * 128 + c * 16 + ar) * K_DIM
                               + kbn * BK + ak,
                            &As[tn & 1][c * 512]);
            }
        }

        if (kb == 0) {
            #pragma unroll
            for (int i = 0; i < 4; ++i)
                #pragma unroll
                for (int j = 0; j < 4; ++j)
                    acc[i][j] = f32x4{0.f, 0.f, 0.f, 0.f};
        }

        bf16x8 af[4], bfr[4];
        #pragma unroll
        for (int i = 0; i < 4; ++i)
            af[i] = *(const bf16x8*)
                &As[t & 1][(wm + i * 16 + lrow) * BK + (lane >> 4) * 8];
        #pragma unroll
        for (int j = 0; j < 4; ++j) {
            const int row = wn + j * 16 + lrow;
            const int pos = (kb * 4 + (lane >> 4)) ^ lx;
            bfr[j] = *(const bf16x8*)&Bs[row * K_DIM + pos * 8];
        }
        #pragma unroll
        for (int i = 0; i < 4; ++i)
            #pragma unroll
            for (int j = 0; j < 4; ++j)
                acc[i][j] = __builtin_amdgcn_mfma_f32_16x16x32_bf16(
                    bfr[j], af[i], acc[i][j], 0, 0, 0);   // swapped: D.row -> n

        // ---- interleaved C stores: 2 per step, previous mp's tile
        if (t >= 8) {
            const int pmp = mp - 1;
            #pragma unroll
            for (int q = 0; q < 2; ++q) {
                const int sidx = kb * 2 + q;          // 0..15 over the mp
                const int i = sidx >> 2;
                const int j = sidx & 3;
                const size_t rowb =
                    (size_t)(pmp * 128 + wm + i * 16 + lrow) * N_DIM;
                *(f32x4*)(C + rowb + (n0 + wn + j * 16 + (lane >> 4) * 4)) =
                    accs[i][j];
            }
        }

        // mp finished: shadow-copy acc so next mp's steps can store it
        if (kb == 7) {
            #pragma unroll
            for (int i = 0; i < 4; ++i)
                #pragma unroll
                for (int j = 0; j < 4; ++j)
                    accs[i][j] = acc[i][j];
        }

        if (t < 31) __syncthreads();
    }

    // ---- final mp (mp=3) stores
    {
        const int ln = (lane >> 4) * 4;
        #pragma unroll
        for (int i = 0; i < 4; ++i) {
            const size_t rowb = (size_t)(3 * 128 + wm + i * 16 + lrow) * N_DIM;
            #pragma unroll
            for (int j = 0; j < 4; ++j)
                *(f32x4*)(C + rowb + (n0 + wn + j * 16 + ln)) = accs[i][j];
        }
    }
}

extern "C" void kernel_launch(void* const* d_in, const int* in_sizes, int n_in,
                              void* d_out, int out_size, void* d_ws, size_t ws_size,
                              hipStream_t stream) {
    // setup_inputs order: inputs, indexes, features, mIoU, IoU
    const float* inputs   = (const float*)d_in[0];
    const float* features = (const float*)d_in[2];
    float* out = (float*)d_out;
    __bf16* Aw = (__bf16*)d_ws;          // 256 KB of workspace

    hipLaunchKernelGGL(cvt_inputs, dim3(M_DIM * K_DIM / (256 * 8)), dim3(256),
                       0, stream, inputs, Aw);

    hipLaunchKernelGGL(hm_gemm_bt, dim3(N_DIM / BN), dim3(256), 0, stream,
                       Aw, features, out);
}